// Round 7
// baseline (281.473 us; speedup 1.0000x reference)
//
#include <hip/hip_runtime.h>
#include <math.h>

// Problem constants
#define KS 11
#define H 512
#define W 512
#define OH 502
#define OW 502
#define NPLANES 48
#define TOTAL_OUT (NPLANES * OH * OW)   // 12,096,192

// Structure: one-wave (64-thread) blocks, no LDS, no barriers.
// Lane owns 2 output cols (c, c+1). Per input row: load cols c..c+11
// (6 aligned float2 per input; overlapping windows served by L1),
// horizontal 11-tap conv of 5 signals in registers, push into an
// 11-deep register ring. Then vertical 11-tap FIR over the ring emits
// one output row per input row (1.0x redundancy). Phase loop unrolled
// mod-11 so every ring index constant-folds (ring stays in VGPRs).
#define BAND 33          // output rows per block
#define NBANDS 16        // 16*33 = 528 >= 502 (tail masked)
#define NSTRIPS 4        // 4*128 = 512 col slots >= 502 (tail masked)
#define NTHREADS 64      // ONE wave

__global__ void zero_out_kernel(float* out) { out[0] = 0.0f; }

__global__ __launch_bounds__(NTHREADS) void ssim_kernel(
    const float* __restrict__ x,
    const float* __restrict__ y,
    const float* __restrict__ win,
    float* __restrict__ out)
{
    const int t     = threadIdx.x;
    const int strip = blockIdx.x;             // 0..3
    const int band  = blockIdx.y;             // 0..15
    const int plane = blockIdx.z;             // 0..47
    const int j0    = band * BAND;            // first output row
    const int c     = strip * 128 + 2 * t;    // lane's first col (even)

    const float* __restrict__ xp = x + (size_t)plane * (H * W);
    const float* __restrict__ yp = y + (size_t)plane * (H * W);

    // Separable taps: window = outer(g,g) => g[i] = sqrt(win[i][i]).
    // Uniform loads -> scalar regs.
    float w[KS];
#pragma unroll
    for (int k = 0; k < KS; ++k) w[k] = sqrtf(win[k * (KS + 1)]);

    // Load guards for the 6 float2 windows (cols c+2d, c+2d+1); only
    // strip 3's upper lanes diverge.
    bool lg[6];
#pragma unroll
    for (int d = 0; d < 6; ++d) lg[d] = (c + 2 * d) < W;

    // Ring: 11 rows x [5 signals x 2 cols] of horizontally-convolved values.
    // Layout: [mu_x0, mu_x1, mu_y0, mu_y1, xx0, xx1, yy0, yy1, xy0, xy1]
    float hring[11][10];

    const float c1 = 1e-4f;   // (0.01)^2
    const float c2 = 9e-4f;   // (0.03)^2
    float acc = 0.f;

    // Load row gy, horizontal-conv 5 signals for cols (c, c+1) -> hring[slot]
#define DOROW(gy_, slot_)                                                    \
    {                                                                        \
        const int gy = (gy_);                                                \
        const float2 z2 = make_float2(0.f, 0.f);                             \
        float2 xw[6], yw[6];                                                 \
        if (gy < H) {                                                        \
            const float2* __restrict__ xr = (const float2*)(xp + (size_t)gy * W); \
            const float2* __restrict__ yr = (const float2*)(yp + (size_t)gy * W); \
            const int cb = c >> 1;                                           \
            _Pragma("unroll")                                                \
            for (int d = 0; d < 6; ++d) {                                    \
                xw[d] = lg[d] ? xr[cb + d] : z2;                             \
                yw[d] = lg[d] ? yr[cb + d] : z2;                             \
            }                                                                \
        } else {                                                             \
            _Pragma("unroll")                                                \
            for (int d = 0; d < 6; ++d) { xw[d] = z2; yw[d] = z2; }          \
        }                                                                    \
        float xv[12], yv[12];                                                \
        _Pragma("unroll")                                                    \
        for (int d = 0; d < 6; ++d) {                                        \
            xv[2*d] = xw[d].x; xv[2*d+1] = xw[d].y;                          \
            yv[2*d] = yw[d].x; yv[2*d+1] = yw[d].y;                          \
        }                                                                    \
        float h0=0.f,h1=0.f,h2=0.f,h3=0.f,h4=0.f;                            \
        float g0=0.f,g1=0.f,g2=0.f,g3=0.f,g4=0.f;                            \
        _Pragma("unroll")                                                    \
        for (int m = 0; m < KS; ++m) {                                       \
            const float wk = w[m];                                           \
            { const float a = xv[m],   b = yv[m];                            \
              const float t1 = wk * a, t2 = wk * b;                          \
              h0 += t1; h1 += t2;                                            \
              h2 = fmaf(t1, a, h2); h3 = fmaf(t2, b, h3); h4 = fmaf(t1, b, h4); } \
            { const float a = xv[m+1], b = yv[m+1];                          \
              const float t1 = wk * a, t2 = wk * b;                          \
              g0 += t1; g1 += t2;                                            \
              g2 = fmaf(t1, a, g2); g3 = fmaf(t2, b, g3); g4 = fmaf(t1, b, g4); } \
        }                                                                    \
        hring[slot_][0] = h0; hring[slot_][1] = g0;                          \
        hring[slot_][2] = h1; hring[slot_][3] = g1;                          \
        hring[slot_][4] = h2; hring[slot_][5] = g2;                          \
        hring[slot_][6] = h3; hring[slot_][7] = g3;                          \
        hring[slot_][8] = h4; hring[slot_][9] = g4;                          \
    }

    // Vertical 11-tap over the ring (phase ph_), SSIM for 2 px of row orow_
#define EMIT(ph_, orow_)                                                     \
    {                                                                        \
        const int orow = (orow_);                                            \
        if (orow < OH) {                                                     \
            float mu[10];                                                    \
            _Pragma("unroll")                                                \
            for (int i = 0; i < 10; ++i) mu[i] = 0.f;                        \
            _Pragma("unroll")                                                \
            for (int k = 0; k < KS; ++k) {                                   \
                const float wk = w[k];                                       \
                const int sl = ((ph_) + k) % 11;      /* constant-folds */   \
                _Pragma("unroll")                                            \
                for (int i = 0; i < 10; ++i)                                 \
                    mu[i] = fmaf(wk, hring[sl][i], mu[i]);                   \
            }                                                                \
            _Pragma("unroll")                                                \
            for (int cc = 0; cc < 2; ++cc) {                                 \
                if (c + cc < OW) {                                           \
                    const float ma  = mu[0+cc], mb = mu[2+cc];               \
                    const float sxx = mu[4+cc] - ma * ma;                    \
                    const float syy = mu[6+cc] - mb * mb;                    \
                    const float sxy = mu[8+cc] - ma * mb;                    \
                    const float num = (2.f*sxy + c2) * (2.f*ma*mb + c1);     \
                    const float den = (sxx + syy + c2) * (ma*ma + mb*mb + c1); \
                    acc += num * __builtin_amdgcn_rcpf(den);                 \
                }                                                            \
            }                                                                \
        }                                                                    \
    }

    // ---- Warm-up: rows j0..j0+9 into ring slots 0..9 ----
#pragma unroll
    for (int li = 0; li < 10; ++li) DOROW(j0 + li, li);

    // ---- Main: 3 macro-iters x 11 phases (33 output rows) ----
#pragma unroll 1
    for (int m = 0; m < 3; ++m) {
        const int jb = j0 + 11 * m;
#pragma unroll
        for (int ph = 0; ph < 11; ++ph) {
            DOROW(jb + ph + 10, (ph + 10) % 11);   // slot constant-folds
            EMIT(ph, jb + ph);
        }
    }

    // ---- Wave reduction -> one atomic per block (no LDS, no barrier) ----
#pragma unroll
    for (int off = 32; off > 0; off >>= 1)
        acc += __shfl_down(acc, off, 64);
    if (t == 0) atomicAdd(out, acc * (1.0f / (float)TOTAL_OUT));

#undef DOROW
#undef EMIT
}

extern "C" void kernel_launch(void* const* d_in, const int* in_sizes, int n_in,
                              void* d_out, int out_size, void* d_ws, size_t ws_size,
                              hipStream_t stream)
{
    const float* x   = (const float*)d_in[0];
    const float* y   = (const float*)d_in[1];
    const float* win = (const float*)d_in[2];
    float* out = (float*)d_out;

    zero_out_kernel<<<1, 1, 0, stream>>>(out);

    dim3 grid(NSTRIPS, NBANDS, NPLANES);   // (4, 16, 48) = 3072 one-wave blocks
    ssim_kernel<<<grid, NTHREADS, 0, stream>>>(x, y, win, out);
}